// Round 1
// 3531.678 us; speedup vs baseline: 1.1047x; 1.1047x over previous
//
#include <hip/hip_runtime.h>
#include <hip/hip_fp16.h>
#include <stdint.h>

// Problem constants
#define B_     16
#define T_     1000
#define F_     512
#define H_     512
#define NG_    1024     // 2H
#define M1_    16000    // B*T
#define STEPS_ 2000     // 2T

// ws layout (bytes)
#define WX_OFF     0            // __half[16000*1024] BN'd gates (wz | wh)      32,768,000 B
#define OUTPRE_OFF 32768000     // __half[16000*1024] hidden concat (pre-LN)    32,768,000 B
#define HTAG_OFF   65536000     // uint64_t[16 chains][2 parity][256]              65,536 B

__device__ __forceinline__ int swz(int c) { return c + ((c >> 5) & 3) * 4; }  // LDS bank swizzle

typedef _Float16 h2_t __attribute__((ext_vector_type(2)));
union U32H2 { uint32_t u; h2_t h; };

__device__ __forceinline__ float dot2f(uint32_t a, uint32_t b, float c) {
#if __has_builtin(__builtin_amdgcn_fdot2)
    U32H2 ua, ub; ua.u = a; ub.u = b;
    return __builtin_amdgcn_fdot2(ua.h, ub.h, c, false);
#else
    __half2 ha = *(__half2*)&a, hb = *(__half2*)&b;
    float2 fa = __half22float2(ha), fb = __half22float2(hb);
    return fmaf(fa.x, fb.x, fmaf(fa.y, fb.y, c));
#endif
}

// ---------------------------------------------------------------------------
// init: reset tagged h buffers (h0 = 0 fp16x2, tag 0; parity-1 = sentinel),
// copy x_len. htag packet: [63:32] tag = step t, [31:0] = half2 {h(2p), h(2p+1)}.
// ---------------------------------------------------------------------------
__global__ void init_kernel(uint64_t* __restrict__ htag, const int* __restrict__ xlen,
                            float* __restrict__ out_tail) {
    int i = blockIdx.x * 256 + threadIdx.x;
    if (i < B_ * 2 * 256) {
        uint64_t v = ((i >> 8) & 1) ? 0xFFFFFFFF00000000ULL : 0ULL; // parity1 sentinel / tag0 + fp16 zeros
        __hip_atomic_store(&htag[i], v, __ATOMIC_RELAXED, __HIP_MEMORY_SCOPE_AGENT);
    }
    if (i < B_) out_tail[i] = (float)xlen[i];
}

// ---------------------------------------------------------------------------
// Phase 1: WX[b,t,n] = BN(x[b,t,:] . W[n,:] + bias[n]),  n<512: Wz/z, else Wh/h
// ---------------------------------------------------------------------------
__global__ __launch_bounds__(256) void gemm_gates(
    const float* __restrict__ x, const float* __restrict__ Wz, const float* __restrict__ Wh,
    const float* __restrict__ bz, const float* __restrict__ bh,
    const float* __restrict__ zg, const float* __restrict__ zb, const float* __restrict__ zm, const float* __restrict__ zv,
    const float* __restrict__ hg, const float* __restrict__ hb, const float* __restrict__ hm, const float* __restrict__ hv,
    __half* __restrict__ WX)
{
    __shared__ float As[16][132];
    __shared__ float Bs[16][144];
    int tid = threadIdx.x;
    int bm = blockIdx.x >> 3, bn = blockIdx.x & 7;
    int m0 = bm * 128, n0 = bn * 128;
    bool isZ = (n0 < 512);
    const float* Wsrc = isZ ? Wz : Wh;
    int nc0 = isZ ? n0 : (n0 - 512);
    const float* biasp = isZ ? bz : bh;
    const float* gp = isZ ? zg : hg;  const float* bp = isZ ? zb : hb;
    const float* mp = isZ ? zm : hm;  const float* vp = isZ ? zv : hv;
    int tm = tid >> 4, tn = tid & 15;
    float acc[8][8] = {};

    for (int k0 = 0; k0 < 512; k0 += 16) {
#pragma unroll
        for (int i = 0; i < 2; ++i) {
            int f = tid * 2 + i;
            int row = f >> 2, c4 = (f & 3) * 4;
            float4 v = *(const float4*)(x + (size_t)(m0 + row) * 512 + k0 + c4);
            As[c4 + 0][row] = v.x; As[c4 + 1][row] = v.y;
            As[c4 + 2][row] = v.z; As[c4 + 3][row] = v.w;
        }
#pragma unroll
        for (int i = 0; i < 2; ++i) {
            int f = tid * 2 + i;
            int row = f >> 2, c4 = (f & 3) * 4;
            float4 v = *(const float4*)(Wsrc + (size_t)(nc0 + row) * 512 + k0 + c4);
            int r = swz(row);
            Bs[c4 + 0][r] = v.x; Bs[c4 + 1][r] = v.y;
            Bs[c4 + 2][r] = v.z; Bs[c4 + 3][r] = v.w;
        }
        __syncthreads();
#pragma unroll
        for (int kk = 0; kk < 16; ++kk) {
            float a[8], b[8];
            *(float4*)&a[0] = *(const float4*)&As[kk][tm * 8];
            *(float4*)&a[4] = *(const float4*)&As[kk][tm * 8 + 4];
            *(float4*)&b[0] = *(const float4*)&Bs[kk][swz(tn * 8)];
            *(float4*)&b[4] = *(const float4*)&Bs[kk][swz(tn * 8) + 4];
#pragma unroll
            for (int i = 0; i < 8; ++i)
#pragma unroll
                for (int j = 0; j < 8; ++j)
                    acc[i][j] = fmaf(a[i], b[j], acc[i][j]);
        }
        __syncthreads();
    }

    float sc[8], sh[8];
#pragma unroll
    for (int j = 0; j < 8; ++j) {
        int nc = nc0 + tn * 8 + j;
        float s = gp[nc] * rsqrtf(vp[nc] + 1e-5f);
        sc[j] = s;
        sh[j] = (biasp[nc] - mp[nc]) * s + bp[nc];
    }
#pragma unroll
    for (int i = 0; i < 8; ++i) {
        size_t rowoff = (size_t)(m0 + tm * 8 + i) * NG_ + n0 + tn * 8;
#pragma unroll
        for (int j = 0; j < 4; ++j) {
            float v0 = acc[i][2 * j] * sc[2 * j] + sh[2 * j];
            float v1 = acc[i][2 * j + 1] * sc[2 * j + 1] + sh[2 * j + 1];
            *(__half2*)(WX + rowoff + 2 * j) = __floats2half2_rn(v0, v1);
        }
    }
}

// ---------------------------------------------------------------------------
// Phase 2: LiGRU recurrence. 16 chains x 8 WGs x 512 threads; WG g of chain c
// owns cols [64g, 64g+64). Thread (rg,ck), rg=tid>>4 (0..31), ck=tid&15:
// 4 U-rows {z:2rg, z:2rg+1, h:2rg, h:2rg+1} x K-chunk [32ck,32ck+32) in regs.
// h is published as ONE u64 packet per column pair: tag32 | half2 payload,
// so poll-success == payload-received (single-atom), 4 loads/lane (coalesced).
// LDS h_s is double-buffered by step parity -> ONE barrier per step.
// WX is prefetched TWO steps ahead (cur/nxt regs) so cold-HBM latency never
// lands on the critical path; WX/out_pre use nontemporal ops so the streams
// don't evict the hot htag lines from the XCD L2 the spin loop lives in.
// Race-freedom induction unchanged: publish(t+1) happens-after observe-all(t)
// happens-after every WG's read-complete of parity buffer (t+1)&1 at t-1.
// ---------------------------------------------------------------------------
__global__ __launch_bounds__(512, 1) void recur_kernel(
    const __half* __restrict__ WX, const float* __restrict__ U,
    uint64_t* __restrict__ htag, __half* __restrict__ out_pre)
{
    int bI = blockIdx.x;
    int X  = bI & 7;           // XCD residue (perf heuristic only)
    int s  = bI >> 3;          // 0..15
    int c  = X + 8 * (s & 1);  // chain
    int g  = s >> 1;           // column-group 0..7 (64 cols)
    int tid = threadIdx.x;
    int rg = tid >> 4;         // row-group 0..31 (2 z-rows + 2 h-rows)
    int ck = tid & 15;         // 32-wide K chunk

    // Load 4 U rows x 32-half chunk into fp16x2 registers (64 VGPRs)
    uint32_t ureg[4][16];
    {
        int base = g * 64 + 2 * rg;
        int rows[4] = { base, base + 1, H_ + base, H_ + base + 1 };
#pragma unroll
        for (int r = 0; r < 4; ++r) {
            const float4* up = (const float4*)(U + (size_t)rows[r] * H_ + ck * 32);
#pragma unroll
            for (int q = 0; q < 8; ++q) {
                float4 v = up[q];
                __half2 a = __floats2half2_rn(v.x, v.y);
                __half2 b = __floats2half2_rn(v.z, v.w);
                ureg[r][2 * q]     = *(uint32_t*)&a;
                ureg[r][2 * q + 1] = *(uint32_t*)&b;
            }
        }
    }

    // h fp16 in LDS, double-buffered by step parity:
    // col -> chunk (col>>5) at half-offset chunk*40 + (col&31)
    __shared__ __align__(16) __half h_s[2][16 * 40];

    uint64_t* myb = htag + (size_t)c * 512;   // [2][256]

    bool gate = (ck == 0);
    int j0 = g * 64 + 2 * rg;                  // gate lane's columns j0, j0+1
    float hold0 = 0.f, hold1 = 0.f;            // fp32 recurrent state
    __half2 wzC, whC, wzN, whN;                // WX for step t (C) and t+1 (N)
    if (gate) {
        const __half* w0 = WX + (size_t)(c * T_ + 0) * NG_;   // t=0
        wzC = *(const __half2*)(w0 + j0);
        whC = *(const __half2*)(w0 + H_ + j0);
        const __half* w1 = WX + (size_t)(c * T_ + 1) * NG_;   // t=1
        wzN = *(const __half2*)(w1 + j0);
        whN = *(const __half2*)(w1 + H_ + j0);
    }

    for (int t = 0; t < STEPS_; ++t) {
        uint64_t* buf = myb + (size_t)(t & 1) * 256;
        uint32_t tag = (uint32_t)t;

        if (tid < 64) {        // wave 0: poll all 256 packets (coalesced)
            uint64_t v[4];
#pragma unroll
            for (int k = 0; k < 4; ++k)
                v[k] = __hip_atomic_load(&buf[tid + 64 * k], __ATOMIC_RELAXED,
                                         __HIP_MEMORY_SCOPE_AGENT);
            while (true) {
                uint32_t bad = 0;
#pragma unroll
                for (int k = 0; k < 4; ++k) bad |= ((uint32_t)(v[k] >> 32)) ^ tag;
                if (bad == 0) break;
#pragma unroll
                for (int k = 0; k < 4; ++k)
                    if ((uint32_t)(v[k] >> 32) != tag)
                        v[k] = __hip_atomic_load(&buf[tid + 64 * k], __ATOMIC_RELAXED,
                                                 __HIP_MEMORY_SCOPE_AGENT);
            }
            // stage payload half2 directly (cols 2p, 2p+1 are u32-contiguous)
            uint32_t* hb = (uint32_t*)(h_s[t & 1]);
#pragma unroll
            for (int k = 0; k < 4; ++k) {
                int p = tid + 64 * k;
                hb[(p >> 4) * 20 + (p & 15)] = (uint32_t)v[k];
            }
        }
        __syncthreads();   // h_s[t&1] staged; stragglers of t-1 protected by
                           // this same barrier (they read the OTHER buffer)

        // ---- 4-row x 32-chunk dot (64 B of h, reused x4) ----
        float a0 = 0.f, a1 = 0.f, a2 = 0.f, a3 = 0.f;
        const uint4* h4 = (const uint4*)(h_s[t & 1] + ck * 40);
#pragma unroll
        for (int q = 0; q < 4; ++q) {
            uint4 hv = h4[q];
            a0 = dot2f(ureg[0][4 * q + 0], hv.x, a0);
            a0 = dot2f(ureg[0][4 * q + 1], hv.y, a0);
            a0 = dot2f(ureg[0][4 * q + 2], hv.z, a0);
            a0 = dot2f(ureg[0][4 * q + 3], hv.w, a0);
            a1 = dot2f(ureg[1][4 * q + 0], hv.x, a1);
            a1 = dot2f(ureg[1][4 * q + 1], hv.y, a1);
            a1 = dot2f(ureg[1][4 * q + 2], hv.z, a1);
            a1 = dot2f(ureg[1][4 * q + 3], hv.w, a1);
            a2 = dot2f(ureg[2][4 * q + 0], hv.x, a2);
            a2 = dot2f(ureg[2][4 * q + 1], hv.y, a2);
            a2 = dot2f(ureg[2][4 * q + 2], hv.z, a2);
            a2 = dot2f(ureg[2][4 * q + 3], hv.w, a2);
            a3 = dot2f(ureg[3][4 * q + 0], hv.x, a3);
            a3 = dot2f(ureg[3][4 * q + 1], hv.y, a3);
            a3 = dot2f(ureg[3][4 * q + 2], hv.z, a3);
            a3 = dot2f(ureg[3][4 * q + 3], hv.w, a3);
        }
#pragma unroll
        for (int m = 1; m < 16; m <<= 1) {
            a0 += __shfl_xor(a0, m);
            a1 += __shfl_xor(a1, m);
            a2 += __shfl_xor(a2, m);
            a3 += __shfl_xor(a3, m);
        }

        // ---- gate lanes: compute + publish immediately (no barrier on path) ----
        if (gate) {
            float2 wz = __half22float2(wzC), wh = __half22float2(whC);
            float z0 = 1.f / (1.f + __expf(-(wz.x + a0)));
            float z1 = 1.f / (1.f + __expf(-(wz.y + a1)));
            float hc0 = fmaxf(wh.x + a2, 0.f);
            float hc1 = fmaxf(wh.y + a3, 0.f);
            float hn0 = z0 * hold0 + (1.f - z0) * hc0;
            float hn1 = z1 * hold1 + (1.f - z1) * hc1;
            hold0 = hn0; hold1 = hn1;
            __half2 hp = __floats2half2_rn(hn0, hn1);
            uint64_t* nb = myb + (size_t)((t + 1) & 1) * 256;
            uint64_t pk = ((uint64_t)(uint32_t)(t + 1) << 32) |
                          (uint64_t)(*(uint32_t*)&hp);
            __hip_atomic_store(&nb[j0 >> 1], pk, __ATOMIC_RELAXED,
                               __HIP_MEMORY_SCOPE_AGENT);
            // rotate WX prefetch: C <- N, issue load for t+2 into N
            wzC = wzN; whC = whN;
            int tn2 = (t + 2 < STEPS_) ? (t + 2) : (STEPS_ - 1);
            int sb = (tn2 < T_) ? c : (B_ - 1 - c);
            int st = (tn2 < T_) ? tn2 : (tn2 - T_);
            const __half* wrow = WX + (size_t)(sb * T_ + st) * NG_;
            uint32_t rz = __builtin_nontemporal_load((const uint32_t*)(wrow + j0));
            uint32_t rh = __builtin_nontemporal_load((const uint32_t*)(wrow + H_ + j0));
            wzN = *(__half2*)&rz;
            whN = *(__half2*)&rh;
            // out_pre store (off critical path, streaming -> nontemporal)
            size_t off;
            if (t < T_) off = ((size_t)(c * T_ + t)) * NG_ + j0;
            else        off = ((size_t)((B_ - 1 - c) * T_ + (t - T_))) * NG_ + H_ + j0;
            __builtin_nontemporal_store(*(uint32_t*)&hp, (uint32_t*)(out_pre + off));
        }
        // no trailing barrier: LDS double-buffer + top-of-loop barrier cover it
    }
}

// ---------------------------------------------------------------------------
// Phase 3a: LayerNorm over last dim (1024), in place on f16 buffer
// ---------------------------------------------------------------------------
__global__ __launch_bounds__(256) void ln_kernel(__half* __restrict__ buf,
                                                 const float* __restrict__ g,
                                                 const float* __restrict__ b) {
    __shared__ float red[2][4];
    int row = blockIdx.x, tid = threadIdx.x;
    __half* p = buf + (size_t)row * NG_ + tid * 4;
    uint2 raw = *(const uint2*)p;
    __half2 h01 = *(__half2*)&raw.x, h23 = *(__half2*)&raw.y;
    float2 f01 = __half22float2(h01), f23 = __half22float2(h23);
    float s = f01.x + f01.y + f23.x + f23.y;
    float ss = fmaf(f01.x, f01.x, fmaf(f01.y, f01.y, fmaf(f23.x, f23.x, f23.y * f23.y)));
#pragma unroll
    for (int m = 32; m >= 1; m >>= 1) { s += __shfl_xor(s, m); ss += __shfl_xor(ss, m); }
    int w = tid >> 6;
    if ((tid & 63) == 0) { red[0][w] = s; red[1][w] = ss; }
    __syncthreads();
    float S = red[0][0] + red[0][1] + red[0][2] + red[0][3];
    float SS = red[1][0] + red[1][1] + red[1][2] + red[1][3];
    float mu = S * (1.f / NG_);
    float var = SS * (1.f / NG_) - mu * mu;
    float rstd = rsqrtf(var + 1e-5f);
    int d = tid * 4;
    float o0 = (f01.x - mu) * rstd * g[d + 0] + b[d + 0];
    float o1 = (f01.y - mu) * rstd * g[d + 1] + b[d + 1];
    float o2 = (f23.x - mu) * rstd * g[d + 2] + b[d + 2];
    float o3 = (f23.y - mu) * rstd * g[d + 3] + b[d + 3];
    __half2 a = __floats2half2_rn(o0, o1), c = __floats2half2_rn(o2, o3);
    uint2 out; out.x = *(uint32_t*)&a; out.y = *(uint32_t*)&c;
    *(uint2*)p = out;
}

// ---------------------------------------------------------------------------
// Phase 3b: projection GEMM: out[m,e] = tanh(LN[m,:] . pjW[e,:] + pjb[e]), fp32 out
// ---------------------------------------------------------------------------
__global__ __launch_bounds__(256) void gemm_proj(
    const __half* __restrict__ Ain, const float* __restrict__ pjW,
    const float* __restrict__ pjb, float* __restrict__ outp)
{
    __shared__ float As[16][132];
    __shared__ float Bs[16][144];
    int tid = threadIdx.x;
    int bm = blockIdx.x >> 3, bn = blockIdx.x & 7;
    int m0 = bm * 128, n0 = bn * 128;
    int tm = tid >> 4, tn = tid & 15;
    float acc[8][8] = {};

    for (int k0 = 0; k0 < 1024; k0 += 16) {
        {
            int row = tid >> 1, hb = (tid & 1) * 8;
            uint4 raw = *(const uint4*)(Ain + (size_t)(m0 + row) * NG_ + k0 + hb);
            const __half2* hp = (const __half2*)&raw;
#pragma unroll
            for (int q = 0; q < 4; ++q) {
                float2 f = __half22float2(hp[q]);
                As[hb + 2 * q][row] = f.x;
                As[hb + 2 * q + 1][row] = f.y;
            }
        }
#pragma unroll
        for (int i = 0; i < 2; ++i) {
            int f = tid * 2 + i;
            int row = f >> 2, c4 = (f & 3) * 4;
            float4 v = *(const float4*)(pjW + (size_t)(n0 + row) * 1024 + k0 + c4);
            int r = swz(row);
            Bs[c4 + 0][r] = v.x; Bs[c4 + 1][r] = v.y;
            Bs[c4 + 2][r] = v.z; Bs[c4 + 3][r] = v.w;
        }
        __syncthreads();
#pragma unroll
        for (int kk = 0; kk < 16; ++kk) {
            float a[8], b[8];
            *(float4*)&a[0] = *(const float4*)&As[kk][tm * 8];
            *(float4*)&a[4] = *(const float4*)&As[kk][tm * 8 + 4];
            *(float4*)&b[0] = *(const float4*)&Bs[kk][swz(tn * 8)];
            *(float4*)&b[4] = *(const float4*)&Bs[kk][swz(tn * 8) + 4];
#pragma unroll
            for (int i = 0; i < 8; ++i)
#pragma unroll
                for (int j = 0; j < 8; ++j)
                    acc[i][j] = fmaf(a[i], b[j], acc[i][j]);
        }
        __syncthreads();
    }

#pragma unroll
    for (int i = 0; i < 8; ++i) {
        size_t rowoff = (size_t)(m0 + tm * 8 + i) * NG_ + n0 + tn * 8;
#pragma unroll
        for (int j = 0; j < 8; ++j) {
            int n = n0 + tn * 8 + j;
            outp[rowoff + j] = tanhf(acc[i][j] + pjb[n]);
        }
    }
}

// ---------------------------------------------------------------------------
extern "C" void kernel_launch(void* const* d_in, const int* in_sizes, int n_in,
                              void* d_out, int out_size, void* d_ws, size_t ws_size,
                              hipStream_t stream) {
    const float* x    = (const float*)d_in[0];
    const int*   xlen = (const int*)  d_in[1];
    const float* Wz   = (const float*)d_in[2];
    const float* bz   = (const float*)d_in[3];
    const float* Wh   = (const float*)d_in[4];
    const float* bh   = (const float*)d_in[5];
    const float* U    = (const float*)d_in[6];
    const float* zg   = (const float*)d_in[7];
    const float* zb   = (const float*)d_in[8];
    const float* zm   = (const float*)d_in[9];
    const float* zv   = (const float*)d_in[10];
    const float* hg   = (const float*)d_in[11];
    const float* hb   = (const float*)d_in[12];
    const float* hm   = (const float*)d_in[13];
    const float* hv   = (const float*)d_in[14];
    const float* lng  = (const float*)d_in[15];
    const float* lnb  = (const float*)d_in[16];
    const float* pjW  = (const float*)d_in[17];
    const float* pjb  = (const float*)d_in[18];

    char* ws = (char*)d_ws;
    __half*   WX      = (__half*)(ws + WX_OFF);
    __half*   out_pre = (__half*)(ws + OUTPRE_OFF);
    uint64_t* htag    = (uint64_t*)(ws + HTAG_OFF);
    float* out = (float*)d_out;

    init_kernel<<<64, 256, 0, stream>>>(htag, xlen, out + (size_t)M1_ * NG_);
    gemm_gates<<<1000, 256, 0, stream>>>(x, Wz, Wh, bz, bh, zg, zb, zm, zv,
                                         hg, hb, hm, hv, WX);
    recur_kernel<<<128, 512, 0, stream>>>(WX, U, htag, out_pre);
    ln_kernel<<<M1_, 256, 0, stream>>>(out_pre, lng, lnb);
    gemm_proj<<<1000, 256, 0, stream>>>(out_pre, pjW, pjb, out);
}